// Round 4
// baseline (153.213 us; speedup 1.0000x reference)
//
#include <hip/hip_runtime.h>

// ---------------------------------------------------------------------------
// DeltaThetaGammaCLEVRN — f32 I/O. Oscillator phases are dead code (amplitude
// ODE is phase-independent, ad0=at0=1 is a fixed point). Per sample:
//   sf[16] = mean_n scene;  g = sigmoid(sf@Ws+bs);  20x: g += .01*(g-g^3)
//   h = relu(beff + [query|g] @ W12);  logits = h@W2+b2; log_softmax.
// Round-4: weights read straight from global (L1-broadcast; every block uses
// the same 36 KB) instead of an LDS mirror -> LDS 75->38 KB -> 4 blocks/CU
// (16 waves/CU vs 8). 16 lanes per sample, 4x4 register tile per thread.
// ---------------------------------------------------------------------------

// global workspace layout (f32 offsets), filled by dtg_prep
#define WS_WQ    0      // [60][64] Wq_fold = query_w @ ro_w1[88:152]
#define WS_BEFF  3840   // [64] b_eff = ro_b1 + colsum(ro_w1[0:24]) + qb @ ro_w1[88:152]

__global__ __launch_bounds__(256) void dtg_prep(
    const float* __restrict__ qw, const float* __restrict__ qb,
    const float* __restrict__ w1, const float* __restrict__ b1,
    float* __restrict__ ws)
{
  __shared__ float sm[256];
  const int blk = blockIdx.x, tid = threadIdx.x;
  const int c = tid & 63, p = tid >> 6;
  if (blk < 60) {
    // Wq_fold row k=blk: 64 outputs, 4 partial-threads each (K=64 split by 16)
    float acc = 0.f;
    for (int j = p * 16; j < p * 16 + 16; ++j)
      acc = fmaf(qw[blk * 64 + j], w1[(88 + j) * 64 + c], acc);
    sm[tid] = acc;
    __syncthreads();
    if (tid < 64)
      ws[WS_WQ + blk * 64 + tid] = sm[tid] + sm[64 + tid] + sm[128 + tid] + sm[192 + tid];
  } else {
    float acc = 0.f;
    if (p == 0) {
      acc = b1[c];
      for (int r = 0; r < 24; ++r) acc += w1[r * 64 + c];
    }
    for (int j = p * 16; j < p * 16 + 16; ++j)
      acc = fmaf(qb[j], w1[(88 + j) * 64 + c], acc);
    sm[tid] = acc;
    __syncthreads();
    if (tid < 64)
      ws[WS_BEFF + tid] = sm[tid] + sm[64 + tid] + sm[128 + tid] + sm[192 + tid];
  }
}

// LDS layout (f32 words)
#define L_X2   0                 // [124][68]: rows 0..59 query_t, 60..123 g_t
#define L_SF   (124 * 68)        // [16][68] scene means, transposed
#define L_TOT  (L_SF + 16 * 68)  // 9520 words = 38,080 B -> 4 blocks/CU

// one k-step: x from LDS (broadcast), w from global (L1-shared by all blocks)
#define KSTEP(ACC, XV, WV)                                                     \
  { const float x_[4] = {(XV).x, (XV).y, (XV).z, (XV).w};                      \
    const float w_[4] = {(WV).x, (WV).y, (WV).z, (WV).w};                      \
    _Pragma("unroll") for (int si_ = 0; si_ < 4; ++si_)                        \
      _Pragma("unroll") for (int ci_ = 0; ci_ < 4; ++ci_)                      \
        ACC[si_][ci_] = fmaf(x_[si_], w_[ci_], ACC[si_][ci_]); }

__global__ __launch_bounds__(256, 4) void dtg_main(
    const float* __restrict__ scene,
    const float* __restrict__ query,
    const float* __restrict__ sw,    // scene_w [16][64]
    const float* __restrict__ sb,    // scene_b [64]
    const float* __restrict__ w1,    // ro_w1 [152][64]; rows 24..87 used
    const float* __restrict__ w2,    // ro_w2 [64][2]
    const float* __restrict__ b2,    // ro_b2 [2]
    const float* __restrict__ ws,    // prep: Wq_fold + b_eff
    float* __restrict__ outf)
{
  __shared__ float lds[L_TOT];
  const int tid = threadIdx.x;
  const int blk = blockIdx.x;

  // ---- stage scene -> sf_t[k][68] and query -> q_t rows of X2
  {
    const int s = tid >> 2, q = tid & 3;           // sample-in-block, quad
    const float4* sp = (const float4*)scene + (size_t)blk * 2048;
    float4 a = make_float4(0.f, 0.f, 0.f, 0.f);
#pragma unroll
    for (int n = 0; n < 8; ++n) {
      float4 v = sp[s * 32 + n * 4 + q];
      a.x += v.x; a.y += v.y; a.z += v.z; a.w += v.w;
    }
    lds[L_SF + (4 * q + 0) * 68 + s] = a.x * 0.125f;
    lds[L_SF + (4 * q + 1) * 68 + s] = a.y * 0.125f;
    lds[L_SF + (4 * q + 2) * 68 + s] = a.z * 0.125f;
    lds[L_SF + (4 * q + 3) * 68 + s] = a.w * 0.125f;

    const float4* qp = (const float4*)query + (size_t)blk * 960;  // 64*15 f4
#pragma unroll
    for (int m = 0; m < 4; ++m) {
      int f4i = q + 4 * m;
      if (f4i < 15) {
        float4 v = qp[s * 15 + f4i];
        int k0 = 4 * f4i;
        lds[L_X2 + (k0 + 0) * 68 + s] = v.x;
        lds[L_X2 + (k0 + 1) * 68 + s] = v.y;
        lds[L_X2 + (k0 + 2) * 68 + s] = v.z;
        lds[L_X2 + (k0 + 3) * 68 + s] = v.w;
      }
    }
  }
  __syncthreads();

  // ---- thread = (sgrp: 4 samples) x (cgrp: 4 cols)
  const int sgrp = tid >> 4, cgrp = tid & 15;
  const float4* swp = (const float4*)sw;               // [16][16] f4
  const float4* wqp = (const float4*)(ws + WS_WQ);     // [60][16] f4
  const float4* w1p = (const float4*)(w1 + 24 * 64);   // [64][16] f4 (rows 24..87)

  // stage 1: g[4s][4c] = bs + sf @ Ws
  float ga[4][4];
  {
    float4 bsv = ((const float4*)sb)[cgrp];
#pragma unroll
    for (int si = 0; si < 4; ++si) {
      ga[si][0] = bsv.x; ga[si][1] = bsv.y; ga[si][2] = bsv.z; ga[si][3] = bsv.w;
    }
#pragma unroll 4
    for (int k = 0; k < 16; ++k) {
      float4 xv = *(const float4*)(lds + L_SF + k * 68 + 4 * sgrp);
      float4 wv = swp[k * 16 + cgrp];
      KSTEP(ga, xv, wv)
    }
  }

  // sigmoid + 20 Euler steps of g += 0.01*(g - g^3)
#pragma unroll
  for (int si = 0; si < 4; ++si)
#pragma unroll
    for (int ci = 0; ci < 4; ++ci)
      ga[si][ci] = __builtin_amdgcn_rcpf(1.f + __expf(-ga[si][ci]));
  for (int t = 0; t < 20; ++t) {
#pragma unroll
    for (int si = 0; si < 4; ++si)
#pragma unroll
      for (int ci = 0; ci < 4; ++ci) {
        float a = ga[si][ci];
        ga[si][ci] = fmaf(0.01f, a - a * a * a, a);
      }
  }

  // g -> X2 rows 60+c (transposed, 4 samples contiguous per write)
#pragma unroll
  for (int ci = 0; ci < 4; ++ci) {
    float4 gw = make_float4(ga[0][ci], ga[1][ci], ga[2][ci], ga[3][ci]);
    *(float4*)(lds + L_X2 + (60 + 4 * cgrp + ci) * 68 + 4 * sgrp) = gw;
  }
  __syncthreads();

  // stage 2: h = beff + [q|g] @ W12  (k 0..59 from Wq_fold, 60..123 from ro_w1)
  float ha[4][4];
  {
    float4 bev = *(const float4*)(ws + WS_BEFF + 4 * cgrp);
#pragma unroll
    for (int si = 0; si < 4; ++si) {
      ha[si][0] = bev.x; ha[si][1] = bev.y; ha[si][2] = bev.z; ha[si][3] = bev.w;
    }
#pragma unroll 4
    for (int k = 0; k < 60; ++k) {
      float4 xv = *(const float4*)(lds + L_X2 + k * 68 + 4 * sgrp);
      float4 wv = wqp[k * 16 + cgrp];
      KSTEP(ha, xv, wv)
    }
#pragma unroll 4
    for (int k = 0; k < 64; ++k) {
      float4 xv = *(const float4*)(lds + L_X2 + (60 + k) * 68 + 4 * sgrp);
      float4 wv = w1p[k * 16 + cgrp];
      KSTEP(ha, xv, wv)
    }
  }

  // logits: relu + W2, reduce over the 16 col-lanes (lane bits 0..3)
  float l0[4], l1[4];
  {
    float2 w2c[4];
#pragma unroll
    for (int ci = 0; ci < 4; ++ci)
      w2c[ci] = ((const float2*)w2)[4 * cgrp + ci];
#pragma unroll
    for (int si = 0; si < 4; ++si) {
      float a0 = 0.f, a1 = 0.f;
#pragma unroll
      for (int ci = 0; ci < 4; ++ci) {
        float r = fmaxf(ha[si][ci], 0.f);
        a0 = fmaf(r, w2c[ci].x, a0);
        a1 = fmaf(r, w2c[ci].y, a1);
      }
      l0[si] = a0; l1[si] = a1;
    }
  }
#pragma unroll
  for (int m = 1; m < 16; m <<= 1) {
#pragma unroll
    for (int si = 0; si < 4; ++si) {
      l0[si] += __shfl_xor(l0[si], m);
      l1[si] += __shfl_xor(l1[si], m);
    }
  }
  if (cgrp == 0) {
    const float bb0 = b2[0], bb1 = b2[1];
    const int base = blk * 64 + 4 * sgrp;
    float r[8];
#pragma unroll
    for (int si = 0; si < 4; ++si) {
      float a0 = l0[si] + bb0, a1 = l1[si] + bb1;
      float mx  = fmaxf(a0, a1);
      float e0  = __expf(a0 - mx), e1 = __expf(a1 - mx);
      float lse = mx + __logf(e0 + e1);
      r[2 * si] = a0 - lse; r[2 * si + 1] = a1 - lse;
    }
    float4* op = (float4*)(outf + 2 * base);
    op[0] = make_float4(r[0], r[1], r[2], r[3]);
    op[1] = make_float4(r[4], r[5], r[6], r[7]);
  }
}

extern "C" void kernel_launch(void* const* d_in, const int* in_sizes, int n_in,
                              void* d_out, int out_size, void* d_ws, size_t ws_size,
                              hipStream_t stream)
{
  const float* scene = (const float*)d_in[0];
  const float* query = (const float*)d_in[1];
  // d_in[2..7] = phases/freqs: dead code w.r.t. the output, never read
  const float* sw = (const float*)d_in[8];
  const float* sb = (const float*)d_in[9];
  const float* qw = (const float*)d_in[10];
  const float* qb = (const float*)d_in[11];
  const float* w1 = (const float*)d_in[12];
  const float* b1 = (const float*)d_in[13];
  const float* w2 = (const float*)d_in[14];
  const float* b2 = (const float*)d_in[15];
  float* ws = (float*)d_ws;
  const int B = in_sizes[0] / 128;   // 65536

  hipLaunchKernelGGL(dtg_prep, dim3(61), dim3(256), 0, stream,
                     qw, qb, w1, b1, ws);
  hipLaunchKernelGGL(dtg_main, dim3(B / 64), dim3(256), 0, stream,
                     scene, query, sw, sb, w1, w2, b2, ws, (float*)d_out);
}

// Round 5
// 147.658 us; speedup vs baseline: 1.0376x; 1.0376x over previous
//
#include <hip/hip_runtime.h>

// ---------------------------------------------------------------------------
// DeltaThetaGammaCLEVRN — f32 I/O. Oscillator phases are dead code (amplitude
// ODE is phase-independent, ad0=at0=1 is a fixed point). Per sample:
//   sf[16] = mean_n scene;  g = sigmoid(sf@Ws+bs);  20x: g += .01*(g-g^3)
//   h = relu(beff + [query|g] @ W12);  logits = h@W2+b2; log_softmax.
// Round-5: stage 2 via 16x16x32 bf16 MFMA with split-bf16 compensation
// (Xh*Wh + Xh*Wl + Xl*Wh). W pre-packed into B-fragment lane order (hi+lo)
// by prep2; X staged in LDS in A-fragment (sample-major) order. Replaces the
// 124-step VMEM-latency-bound f32 k-loop (the measured ~60% stall source).
// ---------------------------------------------------------------------------

typedef __attribute__((ext_vector_type(8))) short short8;   // 8 bf16 = 4 VGPR
typedef __attribute__((ext_vector_type(4))) float f32x4;

__device__ __forceinline__ unsigned short f2bf(float f) {
  unsigned u = __float_as_uint(f);
  return (unsigned short)((u + 0x7FFFu + ((u >> 16) & 1u)) >> 16);   // RNE
}
__device__ __forceinline__ float bf2f(unsigned short s) {
  return __uint_as_float(((unsigned)s) << 16);
}

// d_ws layout (f32 word offsets)
#define WS_WQ    0      // [60][64] Wq_fold = query_w @ ro_w1[88:152]
#define WS_BEFF  3840   // [64] b_eff
#define WS_WHF   3904   // 16 frags x 64 lanes x 8 bf16 (hi)  = 4096 words
#define WS_WLF   8000   // 16 frags x 64 lanes x 8 bf16 (lo)  = 4096 words

__global__ __launch_bounds__(256) void dtg_prep(
    const float* __restrict__ qw, const float* __restrict__ qb,
    const float* __restrict__ w1, const float* __restrict__ b1,
    float* __restrict__ ws)
{
  __shared__ float sm[256];
  const int blk = blockIdx.x, tid = threadIdx.x;
  const int c = tid & 63, p = tid >> 6;
  if (blk < 60) {
    float acc = 0.f;
    for (int j = p * 16; j < p * 16 + 16; ++j)
      acc = fmaf(qw[blk * 64 + j], w1[(88 + j) * 64 + c], acc);
    sm[tid] = acc;
    __syncthreads();
    if (tid < 64)
      ws[WS_WQ + blk * 64 + tid] = sm[tid] + sm[64 + tid] + sm[128 + tid] + sm[192 + tid];
  } else {
    float acc = 0.f;
    if (p == 0) {
      acc = b1[c];
      for (int r = 0; r < 24; ++r) acc += w1[r * 64 + c];
    }
    for (int j = p * 16; j < p * 16 + 16; ++j)
      acc = fmaf(qb[j], w1[(88 + j) * 64 + c], acc);
    sm[tid] = acc;
    __syncthreads();
    if (tid < 64)
      ws[WS_BEFF + tid] = sm[tid] + sm[64 + tid] + sm[128 + tid] + sm[192 + tid];
  }
}

// Pack W12 (k 0..59 = Wq_fold, 60..123 = ro_w1 rows 24..87, 124..127 = 0)
// into MFMA B-fragment lane order: frag (nt,kk), lane l: element j =
// W[kk*32 + (l>>4)*8 + j][nt*16 + (l&15)], bf16 hi + lo.
__global__ __launch_bounds__(256) void dtg_prep2(
    const float* __restrict__ w1, float* __restrict__ ws)
{
  const int tid = threadIdx.x;
  unsigned short* dh = (unsigned short*)(ws + WS_WHF);
  unsigned short* dl = (unsigned short*)(ws + WS_WLF);
  for (int it = 0; it < 4; ++it) {
    const int idx  = it * 256 + tid;          // (frag, lane) pair
    const int frag = idx >> 6, lane = idx & 63;
    const int nt = frag >> 2, kk = frag & 3;
    const int n = nt * 16 + (lane & 15), q = lane >> 4;
    unsigned short hh[8], ll[8];
#pragma unroll
    for (int j = 0; j < 8; ++j) {
      const int k = kk * 32 + q * 8 + j;
      float w;
      if      (k < 60)  w = ws[WS_WQ + k * 64 + n];
      else if (k < 124) w = w1[(24 + k - 60) * 64 + n];
      else              w = 0.f;
      hh[j] = f2bf(w);
      ll[j] = f2bf(w - bf2f(hh[j]));
    }
#pragma unroll
    for (int j = 0; j < 8; ++j) { dh[idx * 8 + j] = hh[j]; dl[idx * 8 + j] = ll[j]; }
  }
}

// LDS layout (bytes)
#define XH_OFF 0                   // Xh [64 rows][128 k] bf16, row stride 272 B
#define XL_OFF 17408               // Xl [64 rows][ 64 k] bf16, row stride 144 B
#define SF_OFF 26624               // sf [16][68] f32 (scene means, transposed)
#define L_BYTES (26624 + 16*68*4)  // 30,976 B -> 5 blocks/CU

#define KSTEP(ACC, XV, WV)                                                     \
  { const float x_[4] = {(XV).x, (XV).y, (XV).z, (XV).w};                      \
    const float w_[4] = {(WV).x, (WV).y, (WV).z, (WV).w};                      \
    _Pragma("unroll") for (int si_ = 0; si_ < 4; ++si_)                        \
      _Pragma("unroll") for (int ci_ = 0; ci_ < 4; ++ci_)                      \
        ACC[si_][ci_] = fmaf(x_[si_], w_[ci_], ACC[si_][ci_]); }

__global__ __launch_bounds__(256) void dtg_main(
    const float* __restrict__ scene,
    const float* __restrict__ query,
    const float* __restrict__ sw,    // scene_w [16][64]
    const float* __restrict__ sb,    // scene_b [64]
    const float* __restrict__ w2,    // ro_w2 [64][2]
    const float* __restrict__ b2,    // ro_b2 [2]
    const float* __restrict__ ws,
    float* __restrict__ outf)
{
  __shared__ __align__(16) char smem[L_BYTES];
  const int tid = threadIdx.x;
  const int blk = blockIdx.x;
  float* sf = (float*)(smem + SF_OFF);

  // ---- phase A: scene mean -> sf_t; query -> Xh/Xl rows (A-layout, no transpose)
  {
    const int s = tid >> 2, q = tid & 3;             // sample, quad
    const float4* sp = (const float4*)scene + (size_t)blk * 2048;
    float4 a = make_float4(0.f, 0.f, 0.f, 0.f);
#pragma unroll
    for (int n = 0; n < 8; ++n) {
      float4 v = sp[s * 32 + n * 4 + q];
      a.x += v.x; a.y += v.y; a.z += v.z; a.w += v.w;
    }
    sf[(4 * q + 0) * 68 + s] = a.x * 0.125f;
    sf[(4 * q + 1) * 68 + s] = a.y * 0.125f;
    sf[(4 * q + 2) * 68 + s] = a.z * 0.125f;
    sf[(4 * q + 3) * 68 + s] = a.w * 0.125f;

    const float4* qp = (const float4*)query + (size_t)blk * 960;
#pragma unroll
    for (int m = 0; m < 4; ++m) {
      const int f4i = q + 4 * m;
      if (f4i < 15) {
        float4 v = qp[s * 15 + f4i];
        const float xs[4] = {v.x, v.y, v.z, v.w};
        unsigned short h[4], l[4];
#pragma unroll
        for (int j = 0; j < 4; ++j) {
          h[j] = f2bf(xs[j]);
          l[j] = f2bf(xs[j] - bf2f(h[j]));
        }
        uint2 ph, pl;
        ph.x = (unsigned)h[0] | ((unsigned)h[1] << 16);
        ph.y = (unsigned)h[2] | ((unsigned)h[3] << 16);
        pl.x = (unsigned)l[0] | ((unsigned)l[1] << 16);
        pl.y = (unsigned)l[2] | ((unsigned)l[3] << 16);
        *(uint2*)(smem + XH_OFF + s * 272 + f4i * 8) = ph;
        *(uint2*)(smem + XL_OFF + s * 144 + f4i * 8) = pl;
      }
    }
    if (tid < 64) {   // zero pads: Xh k 124..127, Xl k 60..63
      *(uint2*)(smem + XH_OFF + tid * 272 + 248) = make_uint2(0u, 0u);
      *(uint2*)(smem + XL_OFF + tid * 144 + 120) = make_uint2(0u, 0u);
    }
  }
  __syncthreads();

  // ---- phase B: stage-1 f32 (4x4 tile) + sigmoid + Euler, g -> Xh rows 60..123
  const int sgrp = tid >> 4, cgrp = tid & 15;
  {
    float ga[4][4];
    float4 bsv = ((const float4*)sb)[cgrp];
#pragma unroll
    for (int si = 0; si < 4; ++si) {
      ga[si][0] = bsv.x; ga[si][1] = bsv.y; ga[si][2] = bsv.z; ga[si][3] = bsv.w;
    }
    const float4* swp = (const float4*)sw;
#pragma unroll 4
    for (int k = 0; k < 16; ++k) {
      float4 xv = *(const float4*)(sf + k * 68 + 4 * sgrp);
      float4 wv = swp[k * 16 + cgrp];
      KSTEP(ga, xv, wv)
    }
#pragma unroll
    for (int si = 0; si < 4; ++si)
#pragma unroll
      for (int ci = 0; ci < 4; ++ci)
        ga[si][ci] = __builtin_amdgcn_rcpf(1.f + __expf(-ga[si][ci]));
    for (int st = 0; st < 20; ++st) {
#pragma unroll
      for (int si = 0; si < 4; ++si)
#pragma unroll
        for (int ci = 0; ci < 4; ++ci) {
          float a = ga[si][ci];
          ga[si][ci] = fmaf(0.01f, a - a * a * a, a);
        }
    }
#pragma unroll
    for (int si = 0; si < 4; ++si) {   // 4 bf16 (cols 4cgrp..+3), hi only
      uint2 pw;
      pw.x = (unsigned)f2bf(ga[si][0]) | ((unsigned)f2bf(ga[si][1]) << 16);
      pw.y = (unsigned)f2bf(ga[si][2]) | ((unsigned)f2bf(ga[si][3]) << 16);
      *(uint2*)(smem + XH_OFF + (4 * sgrp + si) * 272 + 120 + 8 * cgrp) = pw;
    }
  }
  __syncthreads();

  // ---- phase C: MFMA. wave -> 16 samples x all 64 cols, K=128.
  const int wv   = tid >> 6, lane = tid & 63;
  const int quad = lane >> 4;
  const int mrow = wv * 16 + (lane & 15);
  const char* arow = smem + XH_OFF + mrow * 272 + quad * 16;
  short8 Ah0 = *(const short8*)(arow + 0);
  short8 Ah1 = *(const short8*)(arow + 64);
  short8 Ah2 = *(const short8*)(arow + 128);
  short8 Ah3 = *(const short8*)(arow + 192);
  const char* lrow = smem + XL_OFF + mrow * 144 + quad * 16;
  short8 Al0 = *(const short8*)(lrow + 0);
  short8 Al1 = *(const short8*)(lrow + 64);

  const short8* Bh = (const short8*)(ws + WS_WHF);
  const short8* Bl = (const short8*)(ws + WS_WLF);

  float l0[4] = {0.f, 0.f, 0.f, 0.f}, l1[4] = {0.f, 0.f, 0.f, 0.f};
#pragma unroll
  for (int nt = 0; nt < 4; ++nt) {
    const short8* bh = Bh + (nt * 4) * 64 + lane;
    const short8* bl = Bl + (nt * 4) * 64 + lane;
    f32x4 acc = {0.f, 0.f, 0.f, 0.f};
    acc = __builtin_amdgcn_mfma_f32_16x16x32_bf16(Ah0, bh[0],   acc, 0, 0, 0);
    acc = __builtin_amdgcn_mfma_f32_16x16x32_bf16(Ah1, bh[64],  acc, 0, 0, 0);
    acc = __builtin_amdgcn_mfma_f32_16x16x32_bf16(Ah2, bh[128], acc, 0, 0, 0);
    acc = __builtin_amdgcn_mfma_f32_16x16x32_bf16(Ah3, bh[192], acc, 0, 0, 0);
    acc = __builtin_amdgcn_mfma_f32_16x16x32_bf16(Ah0, bl[0],   acc, 0, 0, 0);
    acc = __builtin_amdgcn_mfma_f32_16x16x32_bf16(Ah1, bl[64],  acc, 0, 0, 0);
    acc = __builtin_amdgcn_mfma_f32_16x16x32_bf16(Ah2, bl[128], acc, 0, 0, 0);
    acc = __builtin_amdgcn_mfma_f32_16x16x32_bf16(Ah3, bl[192], acc, 0, 0, 0);
    acc = __builtin_amdgcn_mfma_f32_16x16x32_bf16(Al0, bh[0],   acc, 0, 0, 0);
    acc = __builtin_amdgcn_mfma_f32_16x16x32_bf16(Al1, bh[64],  acc, 0, 0, 0);

    const int col = nt * 16 + (lane & 15);
    const float be = ws[WS_BEFF + col];
    const float2 w2v = ((const float2*)w2)[col];
#pragma unroll
    for (int r = 0; r < 4; ++r) {
      float h = fmaxf(acc[r] + be, 0.f);
      l0[r] = fmaf(h, w2v.x, l0[r]);
      l1[r] = fmaf(h, w2v.y, l1[r]);
    }
  }
  // reduce over the 16 column-lanes (lane bits 0..3)
#pragma unroll
  for (int m = 1; m < 16; m <<= 1) {
#pragma unroll
    for (int r = 0; r < 4; ++r) {
      l0[r] += __shfl_xor(l0[r], m);
      l1[r] += __shfl_xor(l1[r], m);
    }
  }
  if ((lane & 15) == 0) {
    const float bb0 = b2[0], bb1 = b2[1];
    float rr[8];
#pragma unroll
    for (int r = 0; r < 4; ++r) {
      float a0 = l0[r] + bb0, a1 = l1[r] + bb1;
      float mx  = fmaxf(a0, a1);
      float e0  = __expf(a0 - mx), e1 = __expf(a1 - mx);
      float lse = mx + __logf(e0 + e1);
      rr[2 * r] = a0 - lse; rr[2 * r + 1] = a1 - lse;
    }
    const int base = blk * 64 + wv * 16 + quad * 4;    // 4 consecutive samples
    float4* op = (float4*)(outf + base * 2);
    op[0] = make_float4(rr[0], rr[1], rr[2], rr[3]);
    op[1] = make_float4(rr[4], rr[5], rr[6], rr[7]);
  }
}

extern "C" void kernel_launch(void* const* d_in, const int* in_sizes, int n_in,
                              void* d_out, int out_size, void* d_ws, size_t ws_size,
                              hipStream_t stream)
{
  const float* scene = (const float*)d_in[0];
  const float* query = (const float*)d_in[1];
  // d_in[2..7] = phases/freqs: dead code w.r.t. the output, never read
  const float* sw = (const float*)d_in[8];
  const float* sb = (const float*)d_in[9];
  const float* qw = (const float*)d_in[10];
  const float* qb = (const float*)d_in[11];
  const float* w1 = (const float*)d_in[12];
  const float* b1 = (const float*)d_in[13];
  const float* w2 = (const float*)d_in[14];
  const float* b2 = (const float*)d_in[15];
  float* ws = (float*)d_ws;
  const int B = in_sizes[0] / 128;   // 65536

  hipLaunchKernelGGL(dtg_prep,  dim3(61), dim3(256), 0, stream, qw, qb, w1, b1, ws);
  hipLaunchKernelGGL(dtg_prep2, dim3(1),  dim3(256), 0, stream, w1, ws);
  hipLaunchKernelGGL(dtg_main,  dim3(B / 64), dim3(256), 0, stream,
                     scene, query, sw, sb, w2, b2, ws, (float*)d_out);
}

// Round 6
// 147.639 us; speedup vs baseline: 1.0378x; 1.0001x over previous
//
#include <hip/hip_runtime.h>

// ---------------------------------------------------------------------------
// DeltaThetaGammaCLEVRN — f32 I/O. Oscillator phases are dead code (amplitude
// ODE is phase-independent, ad0=at0=1 is a fixed point). Per sample:
//   sf[16] = mean_n scene;  g = sigmoid(sf@Ws+bs);  20x: g += .01*(g-g^3)
//   h = relu(beff + [query|g] @ W12);  logits = h@W2+b2; log_softmax.
// Stage 2 via 16x16x32 bf16 MFMA, split-bf16 compensation (Xh*Wh+Xh*Wl+Xl*Wh).
// Round-6: dtg_prep2 parallelized 1 block -> 16 blocks (one B-fragment per
// block); round-5's single-block prep2 was ~15-20 us of serial latency-bound
// gather on one CU, eating the MFMA win (R5 post-mortem).
// ---------------------------------------------------------------------------

typedef __attribute__((ext_vector_type(8))) short short8;   // 8 bf16 = 4 VGPR
typedef __attribute__((ext_vector_type(4))) float f32x4;

__device__ __forceinline__ unsigned short f2bf(float f) {
  unsigned u = __float_as_uint(f);
  return (unsigned short)((u + 0x7FFFu + ((u >> 16) & 1u)) >> 16);   // RNE
}
__device__ __forceinline__ float bf2f(unsigned short s) {
  return __uint_as_float(((unsigned)s) << 16);
}

// d_ws layout (f32 word offsets)
#define WS_WQ    0      // [60][64] Wq_fold = query_w @ ro_w1[88:152]
#define WS_BEFF  3840   // [64] b_eff
#define WS_WHF   3904   // 16 frags x 64 lanes x 8 bf16 (hi)  = 4096 words
#define WS_WLF   8000   // 16 frags x 64 lanes x 8 bf16 (lo)  = 4096 words

__global__ __launch_bounds__(256) void dtg_prep(
    const float* __restrict__ qw, const float* __restrict__ qb,
    const float* __restrict__ w1, const float* __restrict__ b1,
    float* __restrict__ ws)
{
  __shared__ float sm[256];
  const int blk = blockIdx.x, tid = threadIdx.x;
  const int c = tid & 63, p = tid >> 6;
  if (blk < 60) {
    float acc = 0.f;
    for (int j = p * 16; j < p * 16 + 16; ++j)
      acc = fmaf(qw[blk * 64 + j], w1[(88 + j) * 64 + c], acc);
    sm[tid] = acc;
    __syncthreads();
    if (tid < 64)
      ws[WS_WQ + blk * 64 + tid] = sm[tid] + sm[64 + tid] + sm[128 + tid] + sm[192 + tid];
  } else {
    float acc = 0.f;
    if (p == 0) {
      acc = b1[c];
      for (int r = 0; r < 24; ++r) acc += w1[r * 64 + c];
    }
    for (int j = p * 16; j < p * 16 + 16; ++j)
      acc = fmaf(qb[j], w1[(88 + j) * 64 + c], acc);
    sm[tid] = acc;
    __syncthreads();
    if (tid < 64)
      ws[WS_BEFF + tid] = sm[tid] + sm[64 + tid] + sm[128 + tid] + sm[192 + tid];
  }
}

// Pack W12 (k 0..59 = Wq_fold, 60..123 = ro_w1 rows 24..87, 124..127 = 0)
// into MFMA B-fragment lane order: frag (nt,kk), lane l, element j =
// W[kk*32 + (l>>4)*8 + j][nt*16 + (l&15)], bf16 hi + lo.
// One fragment per block: 16 blocks x 64 lanes, 8 elements/thread.
__global__ __launch_bounds__(64) void dtg_prep2(
    const float* __restrict__ w1, float* __restrict__ ws)
{
  const int frag = blockIdx.x;            // 0..15
  const int lane = threadIdx.x;           // 0..63
  const int idx  = frag * 64 + lane;
  const int nt = frag >> 2, kk = frag & 3;
  const int n = nt * 16 + (lane & 15), q = lane >> 4;
  unsigned short* dh = (unsigned short*)(ws + WS_WHF);
  unsigned short* dl = (unsigned short*)(ws + WS_WLF);
  unsigned short hh[8], ll[8];
#pragma unroll
  for (int j = 0; j < 8; ++j) {
    const int k = kk * 32 + q * 8 + j;
    float w;
    if      (k < 60)  w = ws[WS_WQ + k * 64 + n];
    else if (k < 124) w = w1[(24 + k - 60) * 64 + n];
    else              w = 0.f;
    hh[j] = f2bf(w);
    ll[j] = f2bf(w - bf2f(hh[j]));
  }
#pragma unroll
  for (int j = 0; j < 8; ++j) { dh[idx * 8 + j] = hh[j]; dl[idx * 8 + j] = ll[j]; }
}

// LDS layout (bytes)
#define XH_OFF 0                   // Xh [64 rows][128 k] bf16, row stride 272 B
#define XL_OFF 17408               // Xl [64 rows][ 64 k] bf16, row stride 144 B
#define SF_OFF 26624               // sf [16][68] f32 (scene means, transposed)
#define L_BYTES (26624 + 16*68*4)  // 30,976 B -> 5 blocks/CU

#define KSTEP(ACC, XV, WV)                                                     \
  { const float x_[4] = {(XV).x, (XV).y, (XV).z, (XV).w};                      \
    const float w_[4] = {(WV).x, (WV).y, (WV).z, (WV).w};                      \
    _Pragma("unroll") for (int si_ = 0; si_ < 4; ++si_)                        \
      _Pragma("unroll") for (int ci_ = 0; ci_ < 4; ++ci_)                      \
        ACC[si_][ci_] = fmaf(x_[si_], w_[ci_], ACC[si_][ci_]); }

__global__ __launch_bounds__(256) void dtg_main(
    const float* __restrict__ scene,
    const float* __restrict__ query,
    const float* __restrict__ sw,    // scene_w [16][64]
    const float* __restrict__ sb,    // scene_b [64]
    const float* __restrict__ w2,    // ro_w2 [64][2]
    const float* __restrict__ b2,    // ro_b2 [2]
    const float* __restrict__ ws,
    float* __restrict__ outf)
{
  __shared__ __align__(16) char smem[L_BYTES];
  const int tid = threadIdx.x;
  const int blk = blockIdx.x;
  float* sf = (float*)(smem + SF_OFF);

  // ---- phase A: scene mean -> sf_t; query -> Xh/Xl rows (A-layout, no transpose)
  {
    const int s = tid >> 2, q = tid & 3;             // sample, quad
    const float4* sp = (const float4*)scene + (size_t)blk * 2048;
    float4 a = make_float4(0.f, 0.f, 0.f, 0.f);
#pragma unroll
    for (int n = 0; n < 8; ++n) {
      float4 v = sp[s * 32 + n * 4 + q];
      a.x += v.x; a.y += v.y; a.z += v.z; a.w += v.w;
    }
    sf[(4 * q + 0) * 68 + s] = a.x * 0.125f;
    sf[(4 * q + 1) * 68 + s] = a.y * 0.125f;
    sf[(4 * q + 2) * 68 + s] = a.z * 0.125f;
    sf[(4 * q + 3) * 68 + s] = a.w * 0.125f;

    const float4* qp = (const float4*)query + (size_t)blk * 960;
#pragma unroll
    for (int m = 0; m < 4; ++m) {
      const int f4i = q + 4 * m;
      if (f4i < 15) {
        float4 v = qp[s * 15 + f4i];
        const float xs[4] = {v.x, v.y, v.z, v.w};
        unsigned short h[4], l[4];
#pragma unroll
        for (int j = 0; j < 4; ++j) {
          h[j] = f2bf(xs[j]);
          l[j] = f2bf(xs[j] - bf2f(h[j]));
        }
        uint2 ph, pl;
        ph.x = (unsigned)h[0] | ((unsigned)h[1] << 16);
        ph.y = (unsigned)h[2] | ((unsigned)h[3] << 16);
        pl.x = (unsigned)l[0] | ((unsigned)l[1] << 16);
        pl.y = (unsigned)l[2] | ((unsigned)l[3] << 16);
        *(uint2*)(smem + XH_OFF + s * 272 + f4i * 8) = ph;
        *(uint2*)(smem + XL_OFF + s * 144 + f4i * 8) = pl;
      }
    }
    if (tid < 64) {   // zero pads: Xh k 124..127, Xl k 60..63
      *(uint2*)(smem + XH_OFF + tid * 272 + 248) = make_uint2(0u, 0u);
      *(uint2*)(smem + XL_OFF + tid * 144 + 120) = make_uint2(0u, 0u);
    }
  }
  __syncthreads();

  // ---- phase B: stage-1 f32 (4x4 tile) + sigmoid + Euler, g -> Xh rows 60..123
  const int sgrp = tid >> 4, cgrp = tid & 15;
  {
    float ga[4][4];
    float4 bsv = ((const float4*)sb)[cgrp];
#pragma unroll
    for (int si = 0; si < 4; ++si) {
      ga[si][0] = bsv.x; ga[si][1] = bsv.y; ga[si][2] = bsv.z; ga[si][3] = bsv.w;
    }
    const float4* swp = (const float4*)sw;
#pragma unroll 4
    for (int k = 0; k < 16; ++k) {
      float4 xv = *(const float4*)(sf + k * 68 + 4 * sgrp);
      float4 wv = swp[k * 16 + cgrp];
      KSTEP(ga, xv, wv)
    }
#pragma unroll
    for (int si = 0; si < 4; ++si)
#pragma unroll
      for (int ci = 0; ci < 4; ++ci)
        ga[si][ci] = __builtin_amdgcn_rcpf(1.f + __expf(-ga[si][ci]));
    for (int st = 0; st < 20; ++st) {
#pragma unroll
      for (int si = 0; si < 4; ++si)
#pragma unroll
        for (int ci = 0; ci < 4; ++ci) {
          float a = ga[si][ci];
          ga[si][ci] = fmaf(0.01f, a - a * a * a, a);
        }
    }
#pragma unroll
    for (int si = 0; si < 4; ++si) {   // 4 bf16 (cols 4cgrp..+3), hi only
      uint2 pw;
      pw.x = (unsigned)f2bf(ga[si][0]) | ((unsigned)f2bf(ga[si][1]) << 16);
      pw.y = (unsigned)f2bf(ga[si][2]) | ((unsigned)f2bf(ga[si][3]) << 16);
      *(uint2*)(smem + XH_OFF + (4 * sgrp + si) * 272 + 120 + 8 * cgrp) = pw;
    }
  }
  __syncthreads();

  // ---- phase C: MFMA. wave -> 16 samples x all 64 cols, K=128.
  const int wv   = tid >> 6, lane = tid & 63;
  const int quad = lane >> 4;
  const int mrow = wv * 16 + (lane & 15);
  const char* arow = smem + XH_OFF + mrow * 272 + quad * 16;
  short8 Ah0 = *(const short8*)(arow + 0);
  short8 Ah1 = *(const short8*)(arow + 64);
  short8 Ah2 = *(const short8*)(arow + 128);
  short8 Ah3 = *(const short8*)(arow + 192);
  const char* lrow = smem + XL_OFF + mrow * 144 + quad * 16;
  short8 Al0 = *(const short8*)(lrow + 0);
  short8 Al1 = *(const short8*)(lrow + 64);

  const short8* Bh = (const short8*)(ws + WS_WHF);
  const short8* Bl = (const short8*)(ws + WS_WLF);

  float l0[4] = {0.f, 0.f, 0.f, 0.f}, l1[4] = {0.f, 0.f, 0.f, 0.f};
#pragma unroll
  for (int nt = 0; nt < 4; ++nt) {
    const short8* bh = Bh + (nt * 4) * 64 + lane;
    const short8* bl = Bl + (nt * 4) * 64 + lane;
    f32x4 acc = {0.f, 0.f, 0.f, 0.f};
    acc = __builtin_amdgcn_mfma_f32_16x16x32_bf16(Ah0, bh[0],   acc, 0, 0, 0);
    acc = __builtin_amdgcn_mfma_f32_16x16x32_bf16(Ah1, bh[64],  acc, 0, 0, 0);
    acc = __builtin_amdgcn_mfma_f32_16x16x32_bf16(Ah2, bh[128], acc, 0, 0, 0);
    acc = __builtin_amdgcn_mfma_f32_16x16x32_bf16(Ah3, bh[192], acc, 0, 0, 0);
    acc = __builtin_amdgcn_mfma_f32_16x16x32_bf16(Ah0, bl[0],   acc, 0, 0, 0);
    acc = __builtin_amdgcn_mfma_f32_16x16x32_bf16(Ah1, bl[64],  acc, 0, 0, 0);
    acc = __builtin_amdgcn_mfma_f32_16x16x32_bf16(Ah2, bl[128], acc, 0, 0, 0);
    acc = __builtin_amdgcn_mfma_f32_16x16x32_bf16(Ah3, bl[192], acc, 0, 0, 0);
    acc = __builtin_amdgcn_mfma_f32_16x16x32_bf16(Al0, bh[0],   acc, 0, 0, 0);
    acc = __builtin_amdgcn_mfma_f32_16x16x32_bf16(Al1, bh[64],  acc, 0, 0, 0);

    const int col = nt * 16 + (lane & 15);
    const float be = ws[WS_BEFF + col];
    const float2 w2v = ((const float2*)w2)[col];
#pragma unroll
    for (int r = 0; r < 4; ++r) {
      float h = fmaxf(acc[r] + be, 0.f);
      l0[r] = fmaf(h, w2v.x, l0[r]);
      l1[r] = fmaf(h, w2v.y, l1[r]);
    }
  }
  // reduce over the 16 column-lanes (lane bits 0..3)
#pragma unroll
  for (int m = 1; m < 16; m <<= 1) {
#pragma unroll
    for (int r = 0; r < 4; ++r) {
      l0[r] += __shfl_xor(l0[r], m);
      l1[r] += __shfl_xor(l1[r], m);
    }
  }
  if ((lane & 15) == 0) {
    const float bb0 = b2[0], bb1 = b2[1];
    float rr[8];
#pragma unroll
    for (int r = 0; r < 4; ++r) {
      float a0 = l0[r] + bb0, a1 = l1[r] + bb1;
      float mx  = fmaxf(a0, a1);
      float e0  = __expf(a0 - mx), e1 = __expf(a1 - mx);
      float lse = mx + __logf(e0 + e1);
      rr[2 * r] = a0 - lse; rr[2 * r + 1] = a1 - lse;
    }
    const int base = blk * 64 + wv * 16 + quad * 4;    // 4 consecutive samples
    float4* op = (float4*)(outf + base * 2);
    op[0] = make_float4(rr[0], rr[1], rr[2], rr[3]);
    op[1] = make_float4(rr[4], rr[5], rr[6], rr[7]);
  }
}

extern "C" void kernel_launch(void* const* d_in, const int* in_sizes, int n_in,
                              void* d_out, int out_size, void* d_ws, size_t ws_size,
                              hipStream_t stream)
{
  const float* scene = (const float*)d_in[0];
  const float* query = (const float*)d_in[1];
  // d_in[2..7] = phases/freqs: dead code w.r.t. the output, never read
  const float* sw = (const float*)d_in[8];
  const float* sb = (const float*)d_in[9];
  const float* qw = (const float*)d_in[10];
  const float* qb = (const float*)d_in[11];
  const float* w1 = (const float*)d_in[12];
  const float* b1 = (const float*)d_in[13];
  const float* w2 = (const float*)d_in[14];
  const float* b2 = (const float*)d_in[15];
  float* ws = (float*)d_ws;
  const int B = in_sizes[0] / 128;   // 65536

  hipLaunchKernelGGL(dtg_prep,  dim3(61), dim3(256), 0, stream, qw, qb, w1, b1, ws);
  hipLaunchKernelGGL(dtg_prep2, dim3(16), dim3(64),  0, stream, w1, ws);
  hipLaunchKernelGGL(dtg_main,  dim3(B / 64), dim3(256), 0, stream,
                     scene, query, sw, sb, w2, b2, ws, (float*)d_out);
}

// Round 7
// 146.534 us; speedup vs baseline: 1.0456x; 1.0075x over previous
//
#include <hip/hip_runtime.h>

// ---------------------------------------------------------------------------
// DeltaThetaGammaCLEVRN — f32 I/O. Oscillator phases are dead code (amplitude
// ODE is phase-independent, ad0=at0=1 is a fixed point). Per sample:
//   sf[16] = mean_n scene;  g = sigmoid(sf@Ws+bs);  20x: g += .01*(g-g^3)
//   h = relu(beff + [query|g] @ W12);  logits = h@W2+b2; log_softmax.
// Stage 2 via 16x16x32 bf16 MFMA, split-bf16 compensation (Xh*Wh+Xh*Wl+Xl*Wh).
// Round-7: 32-sample blocks (2048 blocks, 128 thr, LDS 15.6 KB -> ~8-10
// resident blocks/CU) so HBM streaming pipelines across blocks instead of
// lockstep-stalling at barriers (R6 post-mortem: grid was exactly 4
// barrier-synchronized blocks/CU -> no overlap of 7.6 us HBM with compute).
// Phase-C B-fragments software-pipelined (prefetch nt+1 during nt's MFMAs).
// ---------------------------------------------------------------------------

typedef __attribute__((ext_vector_type(8))) short short8;   // 8 bf16 = 4 VGPR
typedef __attribute__((ext_vector_type(4))) float f32x4;

__device__ __forceinline__ unsigned short f2bf(float f) {
  unsigned u = __float_as_uint(f);
  return (unsigned short)((u + 0x7FFFu + ((u >> 16) & 1u)) >> 16);   // RNE
}
__device__ __forceinline__ float bf2f(unsigned short s) {
  return __uint_as_float(((unsigned)s) << 16);
}

// d_ws layout (f32 word offsets)
#define WS_WQ    0      // [60][64] Wq_fold = query_w @ ro_w1[88:152]
#define WS_BEFF  3840   // [64] b_eff
#define WS_WHF   3904   // 16 frags x 64 lanes x 8 bf16 (hi)  = 4096 words
#define WS_WLF   8000   // 16 frags x 64 lanes x 8 bf16 (lo)  = 4096 words

__global__ __launch_bounds__(256) void dtg_prep(
    const float* __restrict__ qw, const float* __restrict__ qb,
    const float* __restrict__ w1, const float* __restrict__ b1,
    float* __restrict__ ws)
{
  __shared__ float sm[256];
  const int blk = blockIdx.x, tid = threadIdx.x;
  const int c = tid & 63, p = tid >> 6;
  if (blk < 60) {
    float acc = 0.f;
    for (int j = p * 16; j < p * 16 + 16; ++j)
      acc = fmaf(qw[blk * 64 + j], w1[(88 + j) * 64 + c], acc);
    sm[tid] = acc;
    __syncthreads();
    if (tid < 64)
      ws[WS_WQ + blk * 64 + tid] = sm[tid] + sm[64 + tid] + sm[128 + tid] + sm[192 + tid];
  } else {
    float acc = 0.f;
    if (p == 0) {
      acc = b1[c];
      for (int r = 0; r < 24; ++r) acc += w1[r * 64 + c];
    }
    for (int j = p * 16; j < p * 16 + 16; ++j)
      acc = fmaf(qb[j], w1[(88 + j) * 64 + c], acc);
    sm[tid] = acc;
    __syncthreads();
    if (tid < 64)
      ws[WS_BEFF + tid] = sm[tid] + sm[64 + tid] + sm[128 + tid] + sm[192 + tid];
  }
}

// Pack W12 (k 0..59 = Wq_fold, 60..123 = ro_w1 rows 24..87, 124..127 = 0)
// into MFMA B-fragment lane order: frag (nt,kk), lane l, element j =
// W[kk*32 + (l>>4)*8 + j][nt*16 + (l&15)], bf16 hi + lo.
__global__ __launch_bounds__(64) void dtg_prep2(
    const float* __restrict__ w1, float* __restrict__ ws)
{
  const int frag = blockIdx.x;            // 0..15
  const int lane = threadIdx.x;           // 0..63
  const int idx  = frag * 64 + lane;
  const int nt = frag >> 2, kk = frag & 3;
  const int n = nt * 16 + (lane & 15), q = lane >> 4;
  unsigned short* dh = (unsigned short*)(ws + WS_WHF);
  unsigned short* dl = (unsigned short*)(ws + WS_WLF);
  unsigned short hh[8], ll[8];
#pragma unroll
  for (int j = 0; j < 8; ++j) {
    const int k = kk * 32 + q * 8 + j;
    float w;
    if      (k < 60)  w = ws[WS_WQ + k * 64 + n];
    else if (k < 124) w = w1[(24 + k - 60) * 64 + n];
    else              w = 0.f;
    hh[j] = f2bf(w);
    ll[j] = f2bf(w - bf2f(hh[j]));
  }
#pragma unroll
  for (int j = 0; j < 8; ++j) { dh[idx * 8 + j] = hh[j]; dl[idx * 8 + j] = ll[j]; }
}

// LDS layout (bytes) — 32 samples per block
#define XH_OFF 0                   // Xh [32 rows][128 k] bf16, row stride 272 B
#define XL_OFF 8704                // Xl [32 rows][ 64 k] bf16, row stride 144 B
#define SF_OFF 13312               // sf [16][36] f32 (scene means, transposed)
#define L_BYTES (13312 + 16*36*4)  // 15,616 B

#define KSTEP(ACC, XV, WV)                                                     \
  { const float x_[4] = {(XV).x, (XV).y, (XV).z, (XV).w};                      \
    const float w_[4] = {(WV).x, (WV).y, (WV).z, (WV).w};                      \
    _Pragma("unroll") for (int si_ = 0; si_ < 4; ++si_)                        \
      _Pragma("unroll") for (int ci_ = 0; ci_ < 4; ++ci_)                      \
        ACC[si_][ci_] = fmaf(x_[si_], w_[ci_], ACC[si_][ci_]); }

__global__ __launch_bounds__(128, 4) void dtg_main(
    const float* __restrict__ scene,
    const float* __restrict__ query,
    const float* __restrict__ sw,    // scene_w [16][64]
    const float* __restrict__ sb,    // scene_b [64]
    const float* __restrict__ w2,    // ro_w2 [64][2]
    const float* __restrict__ b2,    // ro_b2 [2]
    const float* __restrict__ ws,
    float* __restrict__ outf)
{
  __shared__ __align__(16) char smem[L_BYTES];
  const int tid = threadIdx.x;
  const int blk = blockIdx.x;
  float* sf = (float*)(smem + SF_OFF);

  // ---- phase A: scene mean -> sf_t; query -> Xh/Xl rows (A-layout)
  {
    const int s = tid >> 2, q = tid & 3;             // sample 0..31, quad
    const float4* sp = (const float4*)scene + (size_t)blk * 1024;
    float4 a = make_float4(0.f, 0.f, 0.f, 0.f);
#pragma unroll
    for (int n = 0; n < 8; ++n) {
      float4 v = sp[s * 32 + n * 4 + q];
      a.x += v.x; a.y += v.y; a.z += v.z; a.w += v.w;
    }
    sf[(4 * q + 0) * 36 + s] = a.x * 0.125f;
    sf[(4 * q + 1) * 36 + s] = a.y * 0.125f;
    sf[(4 * q + 2) * 36 + s] = a.z * 0.125f;
    sf[(4 * q + 3) * 36 + s] = a.w * 0.125f;

    const float4* qp = (const float4*)query + (size_t)blk * 480;  // 32*15 f4
#pragma unroll
    for (int m = 0; m < 4; ++m) {
      const int f4i = q + 4 * m;
      if (f4i < 15) {
        float4 v = qp[s * 15 + f4i];
        const float xs[4] = {v.x, v.y, v.z, v.w};
        unsigned short h[4], l[4];
#pragma unroll
        for (int j = 0; j < 4; ++j) {
          h[j] = f2bf(xs[j]);
          l[j] = f2bf(xs[j] - bf2f(h[j]));
        }
        uint2 ph, pl;
        ph.x = (unsigned)h[0] | ((unsigned)h[1] << 16);
        ph.y = (unsigned)h[2] | ((unsigned)h[3] << 16);
        pl.x = (unsigned)l[0] | ((unsigned)l[1] << 16);
        pl.y = (unsigned)l[2] | ((unsigned)l[3] << 16);
        *(uint2*)(smem + XH_OFF + s * 272 + f4i * 8) = ph;
        *(uint2*)(smem + XL_OFF + s * 144 + f4i * 8) = pl;
      }
    }
    if (tid < 32) {   // zero pads: Xh k 124..127, Xl k 60..63
      *(uint2*)(smem + XH_OFF + tid * 272 + 248) = make_uint2(0u, 0u);
      *(uint2*)(smem + XL_OFF + tid * 144 + 120) = make_uint2(0u, 0u);
    }
  }
  __syncthreads();

  // ---- phase B: stage-1 f32 (4x4 tile) + sigmoid + Euler, g -> Xh rows 60..123
  const int sgrp = tid >> 4, cgrp = tid & 15;        // sgrp 0..7
  {
    float ga[4][4];
    float4 bsv = ((const float4*)sb)[cgrp];
#pragma unroll
    for (int si = 0; si < 4; ++si) {
      ga[si][0] = bsv.x; ga[si][1] = bsv.y; ga[si][2] = bsv.z; ga[si][3] = bsv.w;
    }
    const float4* swp = (const float4*)sw;
#pragma unroll 4
    for (int k = 0; k < 16; ++k) {
      float4 xv = *(const float4*)(sf + k * 36 + 4 * sgrp);
      float4 wv = swp[k * 16 + cgrp];
      KSTEP(ga, xv, wv)
    }
#pragma unroll
    for (int si = 0; si < 4; ++si)
#pragma unroll
      for (int ci = 0; ci < 4; ++ci)
        ga[si][ci] = __builtin_amdgcn_rcpf(1.f + __expf(-ga[si][ci]));
    for (int st = 0; st < 20; ++st) {
#pragma unroll
      for (int si = 0; si < 4; ++si)
#pragma unroll
        for (int ci = 0; ci < 4; ++ci) {
          float a = ga[si][ci];
          ga[si][ci] = fmaf(0.01f, a - a * a * a, a);
        }
    }
#pragma unroll
    for (int si = 0; si < 4; ++si) {   // 4 bf16 (cols 4cgrp..+3), hi only
      uint2 pw;
      pw.x = (unsigned)f2bf(ga[si][0]) | ((unsigned)f2bf(ga[si][1]) << 16);
      pw.y = (unsigned)f2bf(ga[si][2]) | ((unsigned)f2bf(ga[si][3]) << 16);
      *(uint2*)(smem + XH_OFF + (4 * sgrp + si) * 272 + 120 + 8 * cgrp) = pw;
    }
  }
  __syncthreads();

  // ---- phase C: MFMA. wave -> 16 samples x all 64 cols, K=128.
  const int wv   = tid >> 6, lane = tid & 63;
  const int quad = lane >> 4;
  const int mrow = wv * 16 + (lane & 15);
  const char* arow = smem + XH_OFF + mrow * 272 + quad * 16;
  short8 Ah0 = *(const short8*)(arow + 0);
  short8 Ah1 = *(const short8*)(arow + 64);
  short8 Ah2 = *(const short8*)(arow + 128);
  short8 Ah3 = *(const short8*)(arow + 192);
  const char* lrow = smem + XL_OFF + mrow * 144 + quad * 16;
  short8 Al0 = *(const short8*)(lrow + 0);
  short8 Al1 = *(const short8*)(lrow + 64);

  // per-col constants preloaded (8 L2-hot loads, issued together)
  float  be[4];
  float2 w2v4[4];
#pragma unroll
  for (int nt = 0; nt < 4; ++nt) {
    const int col = nt * 16 + (lane & 15);
    be[nt]   = ws[WS_BEFF + col];
    w2v4[nt] = ((const float2*)w2)[col];
  }

  const short8* bhp = (const short8*)(ws + WS_WHF) + lane;
  const short8* blp = (const short8*)(ws + WS_WLF) + lane;
  // prefetch nt=0 fragments
  short8 c0 = bhp[0], c1 = bhp[64], c2 = bhp[128], c3 = bhp[192];
  short8 c4 = blp[0], c5 = blp[64];

  float l0[4] = {0.f, 0.f, 0.f, 0.f}, l1[4] = {0.f, 0.f, 0.f, 0.f};
#pragma unroll
  for (int nt = 0; nt < 4; ++nt) {
    short8 n0 = c0, n1 = c1, n2 = c2, n3 = c3, n4 = c4, n5 = c5;
    if (nt < 3) {                       // prefetch nt+1 during this nt's MFMAs
      const short8* nh = bhp + 256;
      const short8* nl = blp + 256;
      n0 = nh[0]; n1 = nh[64]; n2 = nh[128]; n3 = nh[192];
      n4 = nl[0]; n5 = nl[64];
    }
    f32x4 acc = {0.f, 0.f, 0.f, 0.f};
    acc = __builtin_amdgcn_mfma_f32_16x16x32_bf16(Ah0, c0, acc, 0, 0, 0);
    acc = __builtin_amdgcn_mfma_f32_16x16x32_bf16(Ah1, c1, acc, 0, 0, 0);
    acc = __builtin_amdgcn_mfma_f32_16x16x32_bf16(Ah2, c2, acc, 0, 0, 0);
    acc = __builtin_amdgcn_mfma_f32_16x16x32_bf16(Ah3, c3, acc, 0, 0, 0);
    acc = __builtin_amdgcn_mfma_f32_16x16x32_bf16(Ah0, c4, acc, 0, 0, 0);
    acc = __builtin_amdgcn_mfma_f32_16x16x32_bf16(Ah1, c5, acc, 0, 0, 0);
    acc = __builtin_amdgcn_mfma_f32_16x16x32_bf16(Al0, c0, acc, 0, 0, 0);
    acc = __builtin_amdgcn_mfma_f32_16x16x32_bf16(Al1, c1, acc, 0, 0, 0);
    {
      const short8* bh2p = bhp;  // remaining hi*lo terms: Ah2*Bl2, Ah3*Bl3
      const short8* bl2p = blp;
      short8 x4 = bl2p[128], x5 = bl2p[192];
      acc = __builtin_amdgcn_mfma_f32_16x16x32_bf16(Ah2, x4, acc, 0, 0, 0);
      acc = __builtin_amdgcn_mfma_f32_16x16x32_bf16(Ah3, x5, acc, 0, 0, 0);
      (void)bh2p;
    }
#pragma unroll
    for (int r = 0; r < 4; ++r) {
      float h = fmaxf(acc[r] + be[nt], 0.f);
      l0[r] = fmaf(h, w2v4[nt].x, l0[r]);
      l1[r] = fmaf(h, w2v4[nt].y, l1[r]);
    }
    bhp += 256; blp += 256;
    c0 = n0; c1 = n1; c2 = n2; c3 = n3; c4 = n4; c5 = n5;
  }
  // reduce over the 16 column-lanes (lane bits 0..3)
#pragma unroll
  for (int m = 1; m < 16; m <<= 1) {
#pragma unroll
    for (int r = 0; r < 4; ++r) {
      l0[r] += __shfl_xor(l0[r], m);
      l1[r] += __shfl_xor(l1[r], m);
    }
  }
  if ((lane & 15) == 0) {
    const float bb0 = b2[0], bb1 = b2[1];
    float rr[8];
#pragma unroll
    for (int r = 0; r < 4; ++r) {
      float a0 = l0[r] + bb0, a1 = l1[r] + bb1;
      float mx  = fmaxf(a0, a1);
      float e0  = __expf(a0 - mx), e1 = __expf(a1 - mx);
      float lse = mx + __logf(e0 + e1);
      rr[2 * r] = a0 - lse; rr[2 * r + 1] = a1 - lse;
    }
    const int base = blk * 32 + wv * 16 + quad * 4;    // 4 consecutive samples
    float4* op = (float4*)(outf + base * 2);
    op[0] = make_float4(rr[0], rr[1], rr[2], rr[3]);
    op[1] = make_float4(rr[4], rr[5], rr[6], rr[7]);
  }
}

extern "C" void kernel_launch(void* const* d_in, const int* in_sizes, int n_in,
                              void* d_out, int out_size, void* d_ws, size_t ws_size,
                              hipStream_t stream)
{
  const float* scene = (const float*)d_in[0];
  const float* query = (const float*)d_in[1];
  // d_in[2..7] = phases/freqs: dead code w.r.t. the output, never read
  const float* sw = (const float*)d_in[8];
  const float* sb = (const float*)d_in[9];
  const float* qw = (const float*)d_in[10];
  const float* qb = (const float*)d_in[11];
  const float* w1 = (const float*)d_in[12];
  const float* b1 = (const float*)d_in[13];
  const float* w2 = (const float*)d_in[14];
  const float* b2 = (const float*)d_in[15];
  float* ws = (float*)d_ws;
  const int B = in_sizes[0] / 128;   // 65536

  hipLaunchKernelGGL(dtg_prep,  dim3(61), dim3(256), 0, stream, qw, qb, w1, b1, ws);
  hipLaunchKernelGGL(dtg_prep2, dim3(16), dim3(64),  0, stream, w1, ws);
  hipLaunchKernelGGL(dtg_main,  dim3(B / 32), dim3(128), 0, stream,
                     scene, query, sw, sb, w2, b2, ws, (float*)d_out);
}